// Round 3
// baseline (906.128 us; speedup 1.0000x reference)
//
#include <hip/hip_runtime.h>
#include <cstddef>

#define B_ 64
#define T_ 256
#define C_ 2048
#define H_ 512
#define O_ 11
#define THRESH 1.0f
#define LEAK_ 0.003f
#define OLEAK_ 0.0015f

typedef float v2f __attribute__((ext_vector_type(2)));
typedef float v4f __attribute__((ext_vector_type(4)));

// ---------------------------------------------------------------------------
// Kernel 1: transpose w_rec (H x H) -> w_recT (coalesced recurrent gather).
// ---------------------------------------------------------------------------
__global__ __launch_bounds__(256) void transpose_wrec(const float* __restrict__ w,
                                                      float* __restrict__ wt) {
    __shared__ float tile[32][33];
    int tx = threadIdx.x, ty = threadIdx.y;           // block (32, 8)
    int x = blockIdx.x * 32 + tx;
    int y = blockIdx.y * 32 + ty;
#pragma unroll
    for (int i = 0; i < 32; i += 8)
        tile[ty + i][tx] = w[(size_t)(y + i) * H_ + x];
    __syncthreads();
    int x2 = blockIdx.y * 32 + tx;
    int y2 = blockIdx.x * 32 + ty;
#pragma unroll
    for (int i = 0; i < 32; i += 8)
        wt[(size_t)(y2 + i) * H_ + x2] = tile[tx][ty + i];
}

// ---------------------------------------------------------------------------
// Kernel 2: feedforward GEMM  P[s] = X @ w1^T  over K-chunk s (split-K).
// 128x128 tile, BK=16, 128 threads, 8x16 microtile (6 ds_read_b128 per
// 128 FMA -> LDS off the critical path).  +4-float row skew kills the
// 4-way staging-write bank conflict.  Software-pipelined global->reg->LDS.
// Per-element accumulation order identical to previous version (bit-exact).
// ---------------------------------------------------------------------------
#define BM 128
#define BN 128
#define BK 16
#define LDA (BM + 4)
#define LDB (BN + 4)

template <int S>
__global__ __launch_bounds__(128, 2) void gemm_ff(const float* __restrict__ A,
                                                  const float* __restrict__ Bw,
                                                  float* __restrict__ Pout) {
    const int K = C_;
    const int N = H_;
    const int kLen  = C_ / S;
    const int kBase = blockIdx.z * kLen;

    __shared__ float As[BK][LDA];
    __shared__ float Bs[BK][LDB];

    const int t  = threadIdx.x;
    const int tx = t & 7;         // n-dir (8 groups)
    const int ty = t >> 3;        // m-dir (16 rows of 8)
    const int lr = t >> 2;        // load row 0..31
    const int lc = (t & 3) * 4;   // load k-col 0,4,8,12

    const float* Ap = A  + (size_t)(blockIdx.y * BM + lr) * K + kBase + lc;
    const float* Bp = Bw + (size_t)(blockIdx.x * BN + lr) * K + kBase + lc;

    v2f acc[8][8];
#pragma unroll
    for (int i = 0; i < 8; ++i)
#pragma unroll
        for (int j = 0; j < 8; ++j) acc[i][j] = (v2f){0.f, 0.f};

    float4 ra[4], rb[4];
#pragma unroll
    for (int q = 0; q < 4; ++q) ra[q] = *(const float4*)(Ap + (size_t)(32 * q) * K);
#pragma unroll
    for (int q = 0; q < 4; ++q) rb[q] = *(const float4*)(Bp + (size_t)(32 * q) * K);

    for (int k0 = 0;;) {
        __syncthreads();
#pragma unroll
        for (int q = 0; q < 4; ++q) {
            const int r = lr + 32 * q;
            As[lc + 0][r] = ra[q].x; As[lc + 1][r] = ra[q].y;
            As[lc + 2][r] = ra[q].z; As[lc + 3][r] = ra[q].w;
            Bs[lc + 0][r] = rb[q].x; Bs[lc + 1][r] = rb[q].y;
            Bs[lc + 2][r] = rb[q].z; Bs[lc + 3][r] = rb[q].w;
        }
        __syncthreads();

        k0 += BK;
        const bool more = (k0 < kLen);
        if (more) {
            Ap += BK; Bp += BK;
#pragma unroll
            for (int q = 0; q < 4; ++q) ra[q] = *(const float4*)(Ap + (size_t)(32 * q) * K);
#pragma unroll
            for (int q = 0; q < 4; ++q) rb[q] = *(const float4*)(Bp + (size_t)(32 * q) * K);
        }

#pragma unroll
        for (int k = 0; k < BK; ++k) {
            float4 a0 = *(const float4*)&As[k][ty * 8];
            float4 a1 = *(const float4*)&As[k][ty * 8 + 4];
            float4 b0 = *(const float4*)&Bs[k][tx * 4];
            float4 b1 = *(const float4*)&Bs[k][32 + tx * 4];
            float4 b2 = *(const float4*)&Bs[k][64 + tx * 4];
            float4 b3 = *(const float4*)&Bs[k][96 + tx * 4];
            v2f bv[8] = {{b0.x, b0.y}, {b0.z, b0.w}, {b1.x, b1.y}, {b1.z, b1.w},
                         {b2.x, b2.y}, {b2.z, b2.w}, {b3.x, b3.y}, {b3.z, b3.w}};
            float av[8] = {a0.x, a0.y, a0.z, a0.w, a1.x, a1.y, a1.z, a1.w};
#pragma unroll
            for (int i = 0; i < 8; ++i) {
                v2f ai = {av[i], av[i]};
#pragma unroll
                for (int j = 0; j < 8; ++j) acc[i][j] += ai * bv[j];
            }
        }
        if (!more) break;
    }

    float* P = Pout + (size_t)blockIdx.z * ((size_t)B_ * T_ * H_);
#pragma unroll
    for (int i = 0; i < 8; ++i) {
        const int row = blockIdx.y * BM + ty * 8 + i;
        float* Cp = P + (size_t)row * N + blockIdx.x * BN;
#pragma unroll
        for (int s = 0; s < 4; ++s) {
            v4f c = {acc[i][2 * s].x, acc[i][2 * s].y,
                     acc[i][2 * s + 1].x, acc[i][2 * s + 1].y};
            __builtin_nontemporal_store(c, (v4f*)(Cp + s * 32 + tx * 4));
        }
    }
}

// ---------------------------------------------------------------------------
// Kernel 3: recurrent LIF scan.  One block per batch, 512 threads, 1 neuron
// each.  Double-buffered ballot masks replace the compacted list + prefix
// machinery -> ONE barrier per step, wave-uniform (scalar) bit-scan gather.
// Depth-2 prefetch of split-K partials (nontemporal: keeps wrT L2-resident).
// Summation orders identical to previous version (bit-exact).
// ---------------------------------------------------------------------------
template <int S>
__global__ __launch_bounds__(512) void snn_rec(const float* __restrict__ I1,
                                               const float* __restrict__ wrT,
                                               const float* __restrict__ w2,
                                               float* __restrict__ out) {
    const int b    = blockIdx.x;
    const int h    = threadIdx.x;
    const int lane = h & 63;
    const int w    = h >> 6;

    __shared__ float w2sT[H_ * 12];              // [k][o] stride 12
    __shared__ unsigned long long masks[2][8];   // double-buffered spike masks

#pragma unroll
    for (int o = 0; o < O_; ++o) w2sT[h * 12 + o] = w2[o * H_ + h];
    if (h < 8) { masks[0][h] = 0ull; masks[1][h] = 0ull; }

    float v1 = 0.f;
    float v2 = 0.f;      // live only in h < O_
    float osum = 0.f;

    const float*  i1p  = I1 + (size_t)b * T_ * H_ + h;
    const float*  wr_h = wrT + h;
    const size_t  PARTF = (size_t)B_ * T_ * H_;

    float pfA[S], pfB[S];
#pragma unroll
    for (int s = 0; s < S; ++s) pfA[s] = __builtin_nontemporal_load(i1p + s * PARTF);
#pragma unroll
    for (int s = 0; s < S; ++s) pfB[s] = __builtin_nontemporal_load(i1p + s * PARTF + H_);
    __syncthreads();   // masks zeroed + w2sT staged

    for (int t = 0; t < T_; ++t) {
        const int cur = t & 1;

        float acc = -LEAK_;
        if (cur == 0) {
#pragma unroll
            for (int s = 0; s < S; ++s) acc += pfA[s];
            const size_t tn = (size_t)((t + 2 < T_) ? t + 2 : t);
#pragma unroll
            for (int s = 0; s < S; ++s)
                pfA[s] = __builtin_nontemporal_load(i1p + s * PARTF + tn * H_);
        } else {
#pragma unroll
            for (int s = 0; s < S; ++s) acc += pfB[s];
            const size_t tn = (size_t)((t + 2 < T_) ? t + 2 : t);
#pragma unroll
            for (int s = 0; s < S; ++s)
                pfB[s] = __builtin_nontemporal_load(i1p + s * PARTF + tn * H_);
        }

        // recurrent gather over previous step's spikes (ascending h order,
        // identical to old list order -> bit-exact)
#pragma unroll
        for (int ww = 0; ww < 8; ++ww) {
            unsigned long long m = masks[cur ^ 1][ww];
            while (m) {
                const int idx = (ww << 6) + __builtin_ctzll(m);
                m &= m - 1;
                acc += wr_h[idx * H_];
            }
        }

        // LIF update, subtractive reset
        v1 += acc;
        const bool spike = (v1 >= THRESH);
        if (spike) v1 -= THRESH;

        const unsigned long long bm = __ballot(spike);
        if (lane == 0) masks[cur][w] = bm;
        __syncthreads();           // the ONLY barrier per step

        // output neuron update (11 lanes of wave 0; other waves run ahead)
        if (h < O_) {
            float s2 = 0.f;
#pragma unroll
            for (int ww = 0; ww < 8; ++ww) {
                unsigned long long m = masks[cur][ww];
                while (m) {
                    const int idx = (ww << 6) + __builtin_ctzll(m);
                    m &= m - 1;
                    s2 += w2sT[idx * 12 + h];
                }
            }
            float nv2 = v2 + s2 - OLEAK_;
            v2 = nv2 > 0.f ? nv2 : 0.f;
            osum += v2;
        }
    }
    if (h < O_) out[b * O_ + h] = osum * (1.0f / (float)T_);
}

// ---------------------------------------------------------------------------
extern "C" void kernel_launch(void* const* d_in, const int* in_sizes, int n_in,
                              void* d_out, int out_size, void* d_ws, size_t ws_size,
                              hipStream_t stream) {
    const float* x     = (const float*)d_in[0];   // (B,T,C)
    const float* w1    = (const float*)d_in[1];   // (H,C)
    const float* w_rec = (const float*)d_in[2];   // (H,H)
    const float* w2    = (const float*)d_in[3];   // (O,H)
    float* out = (float*)d_out;                   // (B,O)

    const size_t PART = (size_t)B_ * T_ * H_ * sizeof(float);   // 32 MB
    const size_t WRT  = (size_t)H_ * H_ * sizeof(float);        // 1 MB

    int S = 1;
    if (ws_size >= 4 * PART + WRT) S = 4;
    else if (ws_size >= 2 * PART + WRT) S = 2;

    float* P   = (float*)d_ws;
    float* wrT = (float*)((char*)d_ws + (size_t)S * PART);

    transpose_wrec<<<dim3(H_ / 32, H_ / 32), dim3(32, 8), 0, stream>>>(w_rec, wrT);

    dim3 ggrid(H_ / BN, (B_ * T_) / BM, S);
    switch (S) {
        case 4:
            gemm_ff<4><<<ggrid, dim3(128), 0, stream>>>(x, w1, P);
            snn_rec<4><<<dim3(B_), dim3(H_), 0, stream>>>(P, wrT, w2, out);
            break;
        case 2:
            gemm_ff<2><<<ggrid, dim3(128), 0, stream>>>(x, w1, P);
            snn_rec<2><<<dim3(B_), dim3(H_), 0, stream>>>(P, wrT, w2, out);
            break;
        default:
            gemm_ff<1><<<ggrid, dim3(128), 0, stream>>>(x, w1, P);
            snn_rec<1><<<dim3(B_), dim3(H_), 0, stream>>>(P, wrT, w2, out);
            break;
    }
}

// Round 4
// 782.691 us; speedup vs baseline: 1.1577x; 1.1577x over previous
//
#include <hip/hip_runtime.h>
#include <cstddef>

#define B_ 64
#define T_ 256
#define C_ 2048
#define H_ 512
#define O_ 11
#define THRESH 1.0f
#define LEAK_ 0.003f
#define OLEAK_ 0.0015f

typedef float v2f __attribute__((ext_vector_type(2)));
typedef float v4f __attribute__((ext_vector_type(4)));

// ---------------------------------------------------------------------------
// Kernel 1: transpose w_rec (H x H) -> w_recT (coalesced recurrent gather).
// ---------------------------------------------------------------------------
__global__ __launch_bounds__(256) void transpose_wrec(const float* __restrict__ w,
                                                      float* __restrict__ wt) {
    __shared__ float tile[32][33];
    int tx = threadIdx.x, ty = threadIdx.y;           // block (32, 8)
    int x = blockIdx.x * 32 + tx;
    int y = blockIdx.y * 32 + ty;
#pragma unroll
    for (int i = 0; i < 32; i += 8)
        tile[ty + i][tx] = w[(size_t)(y + i) * H_ + x];
    __syncthreads();
    int x2 = blockIdx.y * 32 + tx;
    int y2 = blockIdx.x * 32 + ty;
#pragma unroll
    for (int i = 0; i < 32; i += 8)
        wt[(size_t)(y2 + i) * H_ + x2] = tile[tx][ty + i];
}

// ---------------------------------------------------------------------------
// Kernel 2: feedforward GEMM  P[s] = X @ w1^T  over K-chunk s (split-K).
// Round-0 proven structure: 256 threads, 128x128 tile, BK=16, 8x8 microtile
// (VGPR-light -> high occupancy), PLUS:
//   * +4-float skew on LDS rows  -> staging writes 4-way -> 2-way (free)
//   * global->reg prefetch pipeline (next tile loads issued before compute)
//   * XCD-chunked block swizzle   -> A-tiles fetched once per XCD, not 4x
//   * nontemporal C stores        -> P stream doesn't pollute L2
// Per-element accumulation order identical to round 0 (bit-exact).
// ---------------------------------------------------------------------------
#define BM 128
#define BN 128
#define BK 16
#define LDT (BM + 4)

template <int S>
__global__ __launch_bounds__(256) void gemm_ff(const float* __restrict__ A,
                                               const float* __restrict__ Bw,
                                               float* __restrict__ Pout) {
    const int K = C_;
    const int N = H_;
    const int kLen = C_ / S;

    // XCD-chunked swizzle: hw linear index i -> logical l so each XCD gets a
    // contiguous chunk (grid = 4 x 128 x S = 512*S blocks, always % 8 == 0).
    const int i  = blockIdx.x + 4 * blockIdx.y + 512 * blockIdx.z;
    const int l  = (i & 7) * (64 * S) + (i >> 3);
    const int bx = l & 3;
    const int by = (l >> 2) & 127;
    const int bz = l >> 9;

    const int kBase = bz * kLen;

    __shared__ float As[BK][LDT];
    __shared__ float Bs[BK][LDT];

    const int t  = threadIdx.x;
    const int tx = t & 15;        // n-dir
    const int ty = t >> 4;        // m-dir
    const int lr = t >> 2;        // load row 0..63
    const int lc = (t & 3) * 4;   // load col 0,4,8,12

    const float* Ap = A  + (size_t)(by * BM + lr) * K + kBase + lc;
    const float* Bp = Bw + (size_t)(bx * BN + lr) * K + kBase + lc;

    v2f acc[8][4];
#pragma unroll
    for (int ii = 0; ii < 8; ++ii)
#pragma unroll
        for (int j = 0; j < 4; ++j) acc[ii][j] = (v2f){0.f, 0.f};

    float4 a0 = *(const float4*)(Ap);
    float4 a1 = *(const float4*)(Ap + (size_t)64 * K);
    float4 b0 = *(const float4*)(Bp);
    float4 b1 = *(const float4*)(Bp + (size_t)64 * K);

    for (int k0 = 0;;) {
        __syncthreads();
        As[lc + 0][lr] = a0.x; As[lc + 1][lr] = a0.y;
        As[lc + 2][lr] = a0.z; As[lc + 3][lr] = a0.w;
        As[lc + 0][lr + 64] = a1.x; As[lc + 1][lr + 64] = a1.y;
        As[lc + 2][lr + 64] = a1.z; As[lc + 3][lr + 64] = a1.w;
        Bs[lc + 0][lr] = b0.x; Bs[lc + 1][lr] = b0.y;
        Bs[lc + 2][lr] = b0.z; Bs[lc + 3][lr] = b0.w;
        Bs[lc + 0][lr + 64] = b1.x; Bs[lc + 1][lr + 64] = b1.y;
        Bs[lc + 2][lr + 64] = b1.z; Bs[lc + 3][lr + 64] = b1.w;
        __syncthreads();

        k0 += BK;
        const bool more = (k0 < kLen);
        if (more) {
            Ap += BK; Bp += BK;
            a0 = *(const float4*)(Ap);
            a1 = *(const float4*)(Ap + (size_t)64 * K);
            b0 = *(const float4*)(Bp);
            b1 = *(const float4*)(Bp + (size_t)64 * K);
        }

#pragma unroll
        for (int k = 0; k < BK; ++k) {
            float4 alo = *(const float4*)&As[k][ty * 4];
            float4 ahi = *(const float4*)&As[k][64 + ty * 4];
            float4 blo = *(const float4*)&Bs[k][tx * 4];
            float4 bhi = *(const float4*)&Bs[k][64 + tx * 4];
            v2f b0v = {blo.x, blo.y}, b1v = {blo.z, blo.w};
            v2f b2v = {bhi.x, bhi.y}, b3v = {bhi.z, bhi.w};
            float av[8] = {alo.x, alo.y, alo.z, alo.w, ahi.x, ahi.y, ahi.z, ahi.w};
#pragma unroll
            for (int ii = 0; ii < 8; ++ii) {
                v2f ai = {av[ii], av[ii]};
                acc[ii][0] += ai * b0v;
                acc[ii][1] += ai * b1v;
                acc[ii][2] += ai * b2v;
                acc[ii][3] += ai * b3v;
            }
        }
        if (!more) break;
    }

    float* P = Pout + (size_t)bz * ((size_t)B_ * T_ * H_);
#pragma unroll
    for (int ii = 0; ii < 8; ++ii) {
        int row = by * BM + (ii < 4 ? ty * 4 + ii : 64 + ty * 4 + (ii - 4));
        float* Cp = P + (size_t)row * N + bx * BN;
        v4f c0 = {acc[ii][0].x, acc[ii][0].y, acc[ii][1].x, acc[ii][1].y};
        v4f c1 = {acc[ii][2].x, acc[ii][2].y, acc[ii][3].x, acc[ii][3].y};
        __builtin_nontemporal_store(c0, (v4f*)(Cp + tx * 4));
        __builtin_nontemporal_store(c1, (v4f*)(Cp + 64 + tx * 4));
    }
}

// ---------------------------------------------------------------------------
// Kernel 3: recurrent LIF scan.  Round-0 proven compacted-list structure
// (ballot + prefix, 2 barriers) — the mask-scan variant serialized the
// gather (1 load in flight) and regressed.  Changes vs round 0:
//   * gather unrolled to 16 loads in flight (was 8)
//   * depth-2 A/B prefetch of split-K partials
//   * nontemporal P loads -> wrT stays L2-resident
// Summation orders identical to round 0 (bit-exact).
// ---------------------------------------------------------------------------
template <int S>
__global__ __launch_bounds__(512) void snn_rec(const float* __restrict__ I1,
                                               const float* __restrict__ wrT,
                                               const float* __restrict__ w2,
                                               float* __restrict__ out) {
    const int b    = blockIdx.x;
    const int h    = threadIdx.x;
    const int lane = h & 63;
    const int w    = h >> 6;

    __shared__ float w2sT[H_ * 12];       // [k][o] stride 12 (conflict-free)
    __shared__ int   lists[2][H_];
    __shared__ int   wcnt[8];
    __shared__ float v2s[O_];
    __shared__ float osum[O_];

#pragma unroll
    for (int o = 0; o < O_; ++o) w2sT[h * 12 + o] = w2[o * H_ + h];
    if (h < O_) { v2s[h] = 0.f; osum[h] = 0.f; }

    float v1 = 0.f;
    int   pc = 0;
    const float*  i1p  = I1 + (size_t)b * T_ * H_ + h;
    const float*  wr_h = wrT + h;
    const size_t  PARTF = (size_t)B_ * T_ * H_;

    float pfA[S], pfB[S];
#pragma unroll
    for (int s = 0; s < S; ++s) pfA[s] = __builtin_nontemporal_load(i1p + s * PARTF);
#pragma unroll
    for (int s = 0; s < S; ++s) pfB[s] = __builtin_nontemporal_load(i1p + s * PARTF + H_);
    __syncthreads();

    for (int t = 0; t < T_; ++t) {
        const int cur = t & 1;

        float acc = -LEAK_;
        if (cur == 0) {
#pragma unroll
            for (int s = 0; s < S; ++s) acc += pfA[s];
            const size_t tn = (size_t)((t + 2 < T_) ? t + 2 : t);
#pragma unroll
            for (int s = 0; s < S; ++s)
                pfA[s] = __builtin_nontemporal_load(i1p + s * PARTF + tn * H_);
        } else {
#pragma unroll
            for (int s = 0; s < S; ++s) acc += pfB[s];
            const size_t tn = (size_t)((t + 2 < T_) ? t + 2 : t);
#pragma unroll
            for (int s = 0; s < S; ++s)
                pfB[s] = __builtin_nontemporal_load(i1p + s * PARTF + tn * H_);
        }

        // recurrent gather: 16 loads in flight, ascending-index add order
        const int* pl = lists[cur ^ 1];
        int j = 0;
        for (; j + 15 < pc; j += 16) {
            const int4 ia = *(const int4*)(pl + j);
            const int4 ib = *(const int4*)(pl + j + 4);
            const int4 ic = *(const int4*)(pl + j + 8);
            const int4 id = *(const int4*)(pl + j + 12);
            float g0 = wr_h[ia.x * H_], g1 = wr_h[ia.y * H_];
            float g2 = wr_h[ia.z * H_], g3 = wr_h[ia.w * H_];
            float g4 = wr_h[ib.x * H_], g5 = wr_h[ib.y * H_];
            float g6 = wr_h[ib.z * H_], g7 = wr_h[ib.w * H_];
            float g8 = wr_h[ic.x * H_], g9 = wr_h[ic.y * H_];
            float gA = wr_h[ic.z * H_], gB = wr_h[ic.w * H_];
            float gC = wr_h[id.x * H_], gD = wr_h[id.y * H_];
            float gE = wr_h[id.z * H_], gF = wr_h[id.w * H_];
            acc += g0; acc += g1; acc += g2; acc += g3;
            acc += g4; acc += g5; acc += g6; acc += g7;
            acc += g8; acc += g9; acc += gA; acc += gB;
            acc += gC; acc += gD; acc += gE; acc += gF;
        }
        for (; j + 7 < pc; j += 8) {
            const int4 ia = *(const int4*)(pl + j);
            const int4 ib = *(const int4*)(pl + j + 4);
            float g0 = wr_h[ia.x * H_], g1 = wr_h[ia.y * H_];
            float g2 = wr_h[ia.z * H_], g3 = wr_h[ia.w * H_];
            float g4 = wr_h[ib.x * H_], g5 = wr_h[ib.y * H_];
            float g6 = wr_h[ib.z * H_], g7 = wr_h[ib.w * H_];
            acc += g0; acc += g1; acc += g2; acc += g3;
            acc += g4; acc += g5; acc += g6; acc += g7;
        }
        for (; j < pc; ++j) acc += wr_h[pl[j] * H_];

        // LIF update, subtractive reset
        v1 += acc;
        const bool spike = (v1 >= THRESH);
        if (spike) v1 -= THRESH;

        // ballot compaction
        unsigned long long m = __ballot(spike);
        int lb = __popcll(m & ((1ull << lane) - 1ull));
        if (lane == 0) wcnt[w] = (int)__popcll(m);
        __syncthreads();                    // B1: wcnt ready

        int base = 0, tot = 0;
#pragma unroll
        for (int ww = 0; ww < 8; ++ww) {
            int c = wcnt[ww];
            if (ww < w) base += c;
            tot += c;
        }
        if (spike) lists[cur][base + lb] = h;
        __syncthreads();                    // B2: list complete

        // output neuron update (11 threads; other waves run ahead to gather)
        if (h < O_) {
            const int* cl = lists[cur];
            float s2 = 0.f;
            for (int j2 = 0; j2 < tot; ++j2) s2 += w2sT[cl[j2] * 12 + h];
            float v2 = v2s[h] + s2 - OLEAK_;
            v2 = v2 > 0.f ? v2 : 0.f;
            v2s[h] = v2;
            osum[h] += v2;
        }
        pc = tot;
    }
    __syncthreads();
    if (h < O_) out[b * O_ + h] = osum[h] * (1.0f / (float)T_);
}

// ---------------------------------------------------------------------------
extern "C" void kernel_launch(void* const* d_in, const int* in_sizes, int n_in,
                              void* d_out, int out_size, void* d_ws, size_t ws_size,
                              hipStream_t stream) {
    const float* x     = (const float*)d_in[0];   // (B,T,C)
    const float* w1    = (const float*)d_in[1];   // (H,C)
    const float* w_rec = (const float*)d_in[2];   // (H,H)
    const float* w2    = (const float*)d_in[3];   // (O,H)
    float* out = (float*)d_out;                   // (B,O)

    const size_t PART = (size_t)B_ * T_ * H_ * sizeof(float);   // 32 MB
    const size_t WRT  = (size_t)H_ * H_ * sizeof(float);        // 1 MB

    int S = 1;
    if (ws_size >= 4 * PART + WRT) S = 4;
    else if (ws_size >= 2 * PART + WRT) S = 2;

    float* P   = (float*)d_ws;
    float* wrT = (float*)((char*)d_ws + (size_t)S * PART);

    transpose_wrec<<<dim3(H_ / 32, H_ / 32), dim3(32, 8), 0, stream>>>(w_rec, wrT);

    dim3 ggrid(H_ / BN, (B_ * T_) / BM, S);
    switch (S) {
        case 4:
            gemm_ff<4><<<ggrid, dim3(256), 0, stream>>>(x, w1, P);
            snn_rec<4><<<dim3(B_), dim3(H_), 0, stream>>>(P, wrT, w2, out);
            break;
        case 2:
            gemm_ff<2><<<ggrid, dim3(256), 0, stream>>>(x, w1, P);
            snn_rec<2><<<dim3(B_), dim3(H_), 0, stream>>>(P, wrT, w2, out);
            break;
        default:
            gemm_ff<1><<<ggrid, dim3(256), 0, stream>>>(x, w1, P);
            snn_rec<1><<<dim3(B_), dim3(H_), 0, stream>>>(P, wrT, w2, out);
            break;
    }
}

// Round 5
// 744.204 us; speedup vs baseline: 1.2176x; 1.0517x over previous
//
#include <hip/hip_runtime.h>
#include <cstddef>

#define B_ 64
#define T_ 256
#define C_ 2048
#define H_ 512
#define O_ 11
#define THRESH 1.0f
#define LEAK_ 0.003f
#define OLEAK_ 0.0015f

typedef float v2f __attribute__((ext_vector_type(2)));

// Raw workgroup barrier: orders LDS ops (lgkmcnt) but does NOT drain vmcnt,
// so prefetched global loads stay in flight across the barrier.
__device__ __forceinline__ void lds_barrier() {
    asm volatile("s_waitcnt lgkmcnt(0)" ::: "memory");
    __builtin_amdgcn_s_barrier();
}

// ---------------------------------------------------------------------------
// Kernel 1: transpose w_rec (H x H) -> w_recT (coalesced recurrent gather).
// ---------------------------------------------------------------------------
__global__ __launch_bounds__(256) void transpose_wrec(const float* __restrict__ w,
                                                      float* __restrict__ wt) {
    __shared__ float tile[32][33];
    int tx = threadIdx.x, ty = threadIdx.y;           // block (32, 8)
    int x = blockIdx.x * 32 + tx;
    int y = blockIdx.y * 32 + ty;
#pragma unroll
    for (int i = 0; i < 32; i += 8)
        tile[ty + i][tx] = w[(size_t)(y + i) * H_ + x];
    __syncthreads();
    int x2 = blockIdx.y * 32 + tx;
    int y2 = blockIdx.x * 32 + ty;
#pragma unroll
    for (int i = 0; i < 32; i += 8)
        wt[(size_t)(y2 + i) * H_ + x2] = tile[tx][ty + i];
}

// ---------------------------------------------------------------------------
// Kernel 2: feedforward GEMM  P[s] = X @ w1^T  over K-chunk s (split-K).
// 256 threads, 128x128 tile, BK=16, 8x8 microtile (proven structure), PLUS:
//   * LDS DOUBLE-BUFFER -> ONE barrier per K-tile (was two; 32 vs 64 total)
//     global loads issue first, FMA on buf p hides latency, stage into p^1
//   * +4-float skew on LDS rows (staging conflicts 4-way -> 2-way = free)
//   * XCD-chunked block swizzle (FETCH 396->70 MB, proven round 4)
//   * plain C stores -> P stays L2/L3-resident for snn_rec
// Per-element FMA accumulation order identical to round 0/4 (bit-exact).
// ---------------------------------------------------------------------------
#define BM 128
#define BN 128
#define BK 16
#define LDT (BM + 4)

template <int S>
__global__ __launch_bounds__(256) void gemm_ff(const float* __restrict__ A,
                                               const float* __restrict__ Bw,
                                               float* __restrict__ Pout) {
    const int K = C_;
    const int N = H_;
    const int kLen = C_ / S;

    // XCD-chunked swizzle (grid = 4*128*S = 512*S blocks, % 8 == 0 always)
    const int i  = blockIdx.x + 4 * blockIdx.y + 512 * blockIdx.z;
    const int l  = (i & 7) * (64 * S) + (i >> 3);
    const int bx = l & 3;
    const int by = (l >> 2) & 127;
    const int bz = l >> 9;
    const int kBase = bz * kLen;

    __shared__ float As[2][BK][LDT];
    __shared__ float Bs[2][BK][LDT];

    const int t  = threadIdx.x;
    const int tx = t & 15;        // n-dir
    const int ty = t >> 4;        // m-dir
    const int lr = t >> 2;        // load row 0..63
    const int lc = (t & 3) * 4;   // load col 0,4,8,12

    const float* Ap = A  + (size_t)(by * BM + lr) * K + kBase + lc;
    const float* Bp = Bw + (size_t)(bx * BN + lr) * K + kBase + lc;

    v2f acc[8][4];
#pragma unroll
    for (int ii = 0; ii < 8; ++ii)
#pragma unroll
        for (int j = 0; j < 4; ++j) acc[ii][j] = (v2f){0.f, 0.f};

    float4 a0 = *(const float4*)(Ap);
    float4 a1 = *(const float4*)(Ap + (size_t)64 * K);
    float4 b0 = *(const float4*)(Bp);
    float4 b1 = *(const float4*)(Bp + (size_t)64 * K);

    auto stage = [&](int pb) {
        As[pb][lc + 0][lr] = a0.x; As[pb][lc + 1][lr] = a0.y;
        As[pb][lc + 2][lr] = a0.z; As[pb][lc + 3][lr] = a0.w;
        As[pb][lc + 0][lr + 64] = a1.x; As[pb][lc + 1][lr + 64] = a1.y;
        As[pb][lc + 2][lr + 64] = a1.z; As[pb][lc + 3][lr + 64] = a1.w;
        Bs[pb][lc + 0][lr] = b0.x; Bs[pb][lc + 1][lr] = b0.y;
        Bs[pb][lc + 2][lr] = b0.z; Bs[pb][lc + 3][lr] = b0.w;
        Bs[pb][lc + 0][lr + 64] = b1.x; Bs[pb][lc + 1][lr + 64] = b1.y;
        Bs[pb][lc + 2][lr + 64] = b1.z; Bs[pb][lc + 3][lr + 64] = b1.w;
    };

    auto compute = [&](int pb) {
#pragma unroll
        for (int k = 0; k < BK; ++k) {
            float4 alo = *(const float4*)&As[pb][k][ty * 4];
            float4 ahi = *(const float4*)&As[pb][k][64 + ty * 4];
            float4 blo = *(const float4*)&Bs[pb][k][tx * 4];
            float4 bhi = *(const float4*)&Bs[pb][k][64 + tx * 4];
            v2f b0v = {blo.x, blo.y}, b1v = {blo.z, blo.w};
            v2f b2v = {bhi.x, bhi.y}, b3v = {bhi.z, bhi.w};
            float av[8] = {alo.x, alo.y, alo.z, alo.w, ahi.x, ahi.y, ahi.z, ahi.w};
#pragma unroll
            for (int ii = 0; ii < 8; ++ii) {
                v2f ai = {av[ii], av[ii]};
                acc[ii][0] += ai * b0v;
                acc[ii][1] += ai * b1v;
                acc[ii][2] += ai * b2v;
                acc[ii][3] += ai * b3v;
            }
        }
    };

    stage(0);
    __syncthreads();

    int p = 0;
    for (int k0 = BK; k0 < kLen; k0 += BK) {
        Ap += BK; Bp += BK;
        a0 = *(const float4*)(Ap);
        a1 = *(const float4*)(Ap + (size_t)64 * K);
        b0 = *(const float4*)(Bp);
        b1 = *(const float4*)(Bp + (size_t)64 * K);
        compute(p);           // FMAs on current buffer hide the global latency
        stage(p ^ 1);         // vmcnt wait folded here, after ~2000 cy of FMA
        lds_barrier();        // ONE barrier per K-tile
        p ^= 1;
    }
    compute(p);

    float* P = Pout + (size_t)bz * ((size_t)B_ * T_ * H_);
#pragma unroll
    for (int ii = 0; ii < 8; ++ii) {
        int row = by * BM + (ii < 4 ? ty * 4 + ii : 64 + ty * 4 + (ii - 4));
        float* Cp = P + (size_t)row * N + bx * BN;
        float4 c0 = {acc[ii][0].x, acc[ii][0].y, acc[ii][1].x, acc[ii][1].y};
        float4 c1 = {acc[ii][2].x, acc[ii][2].y, acc[ii][3].x, acc[ii][3].y};
        *(float4*)(Cp + tx * 4)      = c0;   // plain: keep P L2/L3-resident
        *(float4*)(Cp + 64 + tx * 4) = c1;
    }
}

// ---------------------------------------------------------------------------
// Kernel 3: recurrent LIF scan.  Round-0 proven compacted-list structure,
// with the in-loop __syncthreads (which drain vmcnt and serialized the
// prefetch) replaced by raw lgkmcnt-only barriers: the depth-1 partial-sum
// prefetch now stays in flight across the whole step (~3400 cy).  Plain
// (cached) loads: P is L3-resident after gemm's plain stores.
// Summation orders identical to round 0 (bit-exact).
// ---------------------------------------------------------------------------
template <int S>
__global__ __launch_bounds__(512) void snn_rec(const float* __restrict__ I1,
                                               const float* __restrict__ wrT,
                                               const float* __restrict__ w2,
                                               float* __restrict__ out) {
    const int b    = blockIdx.x;
    const int h    = threadIdx.x;
    const int lane = h & 63;
    const int w    = h >> 6;

    __shared__ float w2sT[H_ * 12];       // [k][o] stride 12 (conflict-free)
    __shared__ int   lists[2][H_];
    __shared__ int   wcnt[8];
    __shared__ float v2s[O_];
    __shared__ float osum[O_];

#pragma unroll
    for (int o = 0; o < O_; ++o) w2sT[h * 12 + o] = w2[o * H_ + h];
    if (h < O_) { v2s[h] = 0.f; osum[h] = 0.f; }

    float v1 = 0.f;
    int   pc = 0;
    const float*  i1p  = I1 + (size_t)b * T_ * H_ + h;
    const float*  wr_h = wrT + h;
    const size_t  PARTF = (size_t)B_ * T_ * H_;

    float pf[S];
#pragma unroll
    for (int s = 0; s < S; ++s) pf[s] = i1p[s * PARTF];   // t=0 prefetch
    __syncthreads();

    for (int t = 0; t < T_; ++t) {
        const int cur = t & 1;

        float acc = -LEAK_;
#pragma unroll
        for (int s = 0; s < S; ++s) acc += pf[s];

        // prefetch next step's feedforward current (stays in flight across
        // the raw barriers below -> latency fully hidden)
        const int tn = (t + 1 < T_) ? t + 1 : t;
#pragma unroll
        for (int s = 0; s < S; ++s) pf[s] = i1p[s * PARTF + (size_t)tn * H_];

        // recurrent gather: 16 loads in flight, ascending-index add order
        const int* pl = lists[cur ^ 1];
        int j = 0;
        for (; j + 15 < pc; j += 16) {
            const int4 ia = *(const int4*)(pl + j);
            const int4 ib = *(const int4*)(pl + j + 4);
            const int4 ic = *(const int4*)(pl + j + 8);
            const int4 id = *(const int4*)(pl + j + 12);
            float g0 = wr_h[ia.x * H_], g1 = wr_h[ia.y * H_];
            float g2 = wr_h[ia.z * H_], g3 = wr_h[ia.w * H_];
            float g4 = wr_h[ib.x * H_], g5 = wr_h[ib.y * H_];
            float g6 = wr_h[ib.z * H_], g7 = wr_h[ib.w * H_];
            float g8 = wr_h[ic.x * H_], g9 = wr_h[ic.y * H_];
            float gA = wr_h[ic.z * H_], gB = wr_h[ic.w * H_];
            float gC = wr_h[id.x * H_], gD = wr_h[id.y * H_];
            float gE = wr_h[id.z * H_], gF = wr_h[id.w * H_];
            acc += g0; acc += g1; acc += g2; acc += g3;
            acc += g4; acc += g5; acc += g6; acc += g7;
            acc += g8; acc += g9; acc += gA; acc += gB;
            acc += gC; acc += gD; acc += gE; acc += gF;
        }
        for (; j + 7 < pc; j += 8) {
            const int4 ia = *(const int4*)(pl + j);
            const int4 ib = *(const int4*)(pl + j + 4);
            float g0 = wr_h[ia.x * H_], g1 = wr_h[ia.y * H_];
            float g2 = wr_h[ia.z * H_], g3 = wr_h[ia.w * H_];
            float g4 = wr_h[ib.x * H_], g5 = wr_h[ib.y * H_];
            float g6 = wr_h[ib.z * H_], g7 = wr_h[ib.w * H_];
            acc += g0; acc += g1; acc += g2; acc += g3;
            acc += g4; acc += g5; acc += g6; acc += g7;
        }
        for (; j < pc; ++j) acc += wr_h[pl[j] * H_];

        // LIF update, subtractive reset
        v1 += acc;
        const bool spike = (v1 >= THRESH);
        if (spike) v1 -= THRESH;

        // ballot compaction
        unsigned long long m = __ballot(spike);
        int lb = __popcll(m & ((1ull << lane) - 1ull));
        if (lane == 0) wcnt[w] = (int)__popcll(m);
        lds_barrier();                      // B1: wcnt ready (no vmcnt drain)

        int base = 0, tot = 0;
#pragma unroll
        for (int ww = 0; ww < 8; ++ww) {
            int c = wcnt[ww];
            if (ww < w) base += c;
            tot += c;
        }
        if (spike) lists[cur][base + lb] = h;
        lds_barrier();                      // B2: list complete (no vmcnt drain)

        // output neuron update (11 threads; other waves run ahead to gather)
        if (h < O_) {
            const int* cl = lists[cur];
            float s2 = 0.f;
            for (int j2 = 0; j2 < tot; ++j2) s2 += w2sT[cl[j2] * 12 + h];
            float v2 = v2s[h] + s2 - OLEAK_;
            v2 = v2 > 0.f ? v2 : 0.f;
            v2s[h] = v2;
            osum[h] += v2;
        }
        pc = tot;
    }
    __syncthreads();
    if (h < O_) out[b * O_ + h] = osum[h] * (1.0f / (float)T_);
}

// ---------------------------------------------------------------------------
extern "C" void kernel_launch(void* const* d_in, const int* in_sizes, int n_in,
                              void* d_out, int out_size, void* d_ws, size_t ws_size,
                              hipStream_t stream) {
    const float* x     = (const float*)d_in[0];   // (B,T,C)
    const float* w1    = (const float*)d_in[1];   // (H,C)
    const float* w_rec = (const float*)d_in[2];   // (H,H)
    const float* w2    = (const float*)d_in[3];   // (O,H)
    float* out = (float*)d_out;                   // (B,O)

    const size_t PART = (size_t)B_ * T_ * H_ * sizeof(float);   // 32 MB
    const size_t WRT  = (size_t)H_ * H_ * sizeof(float);        // 1 MB

    int S = 1;
    if (ws_size >= 4 * PART + WRT) S = 4;
    else if (ws_size >= 2 * PART + WRT) S = 2;

    float* P   = (float*)d_ws;
    float* wrT = (float*)((char*)d_ws + (size_t)S * PART);

    transpose_wrec<<<dim3(H_ / 32, H_ / 32), dim3(32, 8), 0, stream>>>(w_rec, wrT);

    dim3 ggrid(H_ / BN, (B_ * T_) / BM, S);
    switch (S) {
        case 4:
            gemm_ff<4><<<ggrid, dim3(256), 0, stream>>>(x, w1, P);
            snn_rec<4><<<dim3(B_), dim3(H_), 0, stream>>>(P, wrT, w2, out);
            break;
        case 2:
            gemm_ff<2><<<ggrid, dim3(256), 0, stream>>>(x, w1, P);
            snn_rec<2><<<dim3(B_), dim3(H_), 0, stream>>>(P, wrT, w2, out);
            break;
        default:
            gemm_ff<1><<<ggrid, dim3(256), 0, stream>>>(x, w1, P);
            snn_rec<1><<<dim3(B_), dim3(H_), 0, stream>>>(P, wrT, w2, out);
            break;
    }
}